// Round 4
// baseline (509.031 us; speedup 1.0000x reference)
//
#include <hip/hip_runtime.h>

#define RS2f 0.70710678118654752f

// DPP quad_perm encodings: sel0 | sel1<<2 | sel2<<4 | sel3<<6
#define QP_XOR1 0xB1   // [1,0,3,2]
#define QP_XOR2 0x4E   // [2,3,0,1]
#define QP_BC0  0x00
#define QP_BC1  0x55
#define QP_BC2  0xAA
#define QP_BC3  0xFF

template<int CTRL> __device__ __forceinline__ float dppf(float x) {
  return __int_as_float(__builtin_amdgcn_update_dpp(
      0, __float_as_int(x), CTRL, 0xF, 0xF, true));
}

__device__ __forceinline__ float sxor(float x, int sm) {
  return __int_as_float(__float_as_int(x) ^ sm);
}

// lane l picks packed window elements f[5l..5l+4] (f = row-major valid elements, zero-padded)
__device__ __forceinline__ void pick_angles(const float (&P)[4][4], int l, bool hF, bool wF,
                                            float &a0, float &a1, float &a2, float &a3, float &a4) {
  a0=0.f; a1=0.f; a2=0.f; a3=0.f; a4=0.f;
  if (hF && wF) {
    if      (l == 0) { a0=P[0][0]; a1=P[0][1]; a2=P[0][2]; a3=P[0][3]; a4=P[1][0]; }
    else if (l == 1) { a0=P[1][1]; a1=P[1][2]; a2=P[1][3]; a3=P[2][0]; a4=P[2][1]; }
    else if (l == 2) { a0=P[2][2]; a1=P[2][3]; a2=P[3][0]; a3=P[3][1]; a4=P[3][2]; }
    else             { a0=P[3][3]; }
  } else if (hF) {                       // w==2: f = P00,P01,P10,P11,P20,P21,P30,P31
    if      (l == 0) { a0=P[0][0]; a1=P[0][1]; a2=P[1][0]; a3=P[1][1]; a4=P[2][0]; }
    else if (l == 1) { a0=P[2][1]; a1=P[3][0]; a2=P[3][1]; }
  } else if (wF) {                       // h==2: f = P00..P03,P10..P13
    if      (l == 0) { a0=P[0][0]; a1=P[0][1]; a2=P[0][2]; a3=P[0][3]; a4=P[1][0]; }
    else if (l == 1) { a0=P[1][1]; a1=P[1][2]; a2=P[1][3]; }
  } else {                               // h==2,w==2
    if      (l == 0) { a0=P[0][0]; a1=P[0][1]; a2=P[1][0]; a3=P[1][1]; }
  }
}

// Build row0 of U = RZ(a4)RY(a3)RZ(a2)RY(a1)RZ(a0)·H.
// S = chain is SU(2) [[α,β],[−β*,α*]]; track (α,β) only; U row0 = rs2·(α+β, α−β).
// row1 of U = (conj(w1), −conj(w0)) — derived at apply time.
__device__ __forceinline__ void build_gate(float a0, float a1, float a2, float a3, float a4,
                                           float &w0r, float &w0i, float &w1r, float &w1i) {
  float s, c;
  __sincosf(0.5f*a0, &s, &c);
  float ar = c, ai = -s, br = 0.f, bi = 0.f;     // S = RZ(a0)
  // RY(a): α' = cα + sβ*, β' = cβ − sα*
  __sincosf(0.5f*a1, &s, &c);
  { float tar = c*ar + s*br, tai = c*ai - s*bi;
    float tbr = c*br - s*ar, tbi = c*bi + s*ai;
    ar=tar; ai=tai; br=tbr; bi=tbi; }
  // RZ(a): row0 *= e^{-ia/2}
  __sincosf(0.5f*a2, &s, &c);
  { float t;
    t=ar; ar = c*t + s*ai; ai = c*ai - s*t;
    t=br; br = c*t + s*bi; bi = c*bi - s*t; }
  __sincosf(0.5f*a3, &s, &c);
  { float tar = c*ar + s*br, tai = c*ai - s*bi;
    float tbr = c*br - s*ar, tbi = c*bi + s*ai;
    ar=tar; ai=tai; br=tbr; bi=tbi; }
  __sincosf(0.5f*a4, &s, &c);
  { float t;
    t=ar; ar = c*t + s*ai; ai = c*ai - s*t;
    t=br; br = c*t + s*bi; bi = c*bi - s*t; }
  // ·H fold
  w0r = RS2f*(ar+br); w0i = RS2f*(ai+bi);
  w1r = RS2f*(ar-br); w1i = RS2f*(ai-bi);
}

__global__ void __launch_bounds__(256)
quanv_kernel(const float* __restrict__ x,
             const float* __restrict__ crz_t,
             const float* __restrict__ ry_t,
             const float* __restrict__ fc1_w,
             const float* __restrict__ fc1_b,
             const float* __restrict__ fc2_w,
             const float* __restrict__ fc2_b,
             float* __restrict__ out, int B)
{
  __shared__ float sw[20 * 784];
  const int tid = threadIdx.x;
  for (int i = tid; i < (20 * 784) / 4; i += 256)
    ((float4*)sw)[i] = ((const float4*)fc1_w)[i];
  __syncthreads();

  const int l = tid & 3;                       // lane within 4-lane group
  const int b = (blockIdx.x * 256 + tid) >> 2; // element id
  if (b >= B) return;
  const float* img = x + (size_t)b * 784;

  // ---- uniform scalar-derived constants ----
  const float theta = crz_t[0];
  const float ryt   = ry_t[0];
  float cry, sry;
  __sincosf(0.5f * ryt, &sry, &cry);
  const float sgn0 = (l & 2) ? sry : -sry;   // Ry wire0 partner sign (bit = l>>1)
  const float sgn1 = (l & 1) ? sry : -sry;   // Ry wire1 partner sign (bit = l&1)
  // sign masks for SU(2)-derived row1 at apply time
  const int sm0 = (l & 2) ? (int)0x80000000 : 0;  // wire0 row bit
  const int sm1 = (l & 1) ? (int)0x80000000 : 0;  // wire1 row bit

  // CRZ ring diag exp(0.5i*theta*sg[n]) for this lane's 4 amps (n = 4l+k)
  float g0,g1,g2,g3;
  if      (l == 0) { g0= 0.f; g1=-1.f; g2=-1.f; g3=0.f; }
  else if (l == 1) { g0=-1.f; g1=-2.f; g2= 0.f; g3=1.f; }
  else if (l == 2) { g0=-1.f; g1= 0.f; g2=-2.f; g3=1.f; }
  else             { g0= 0.f; g1= 1.f; g2= 1.f; g3=4.f; }
  float czk[4], szk[4];
  __sincosf(0.5f*theta*g0, &szk[0], &czk[0]);
  __sincosf(0.5f*theta*g1, &szk[1], &czk[1]);
  __sincosf(0.5f*theta*g2, &szk[2], &czk[2]);
  __sincosf(0.5f*theta*g3, &szk[3], &czk[3]);

  // state: amp n = 4*l + k  (bits: b0=l>>1, b1=l&1, b2=k>>1, b3=k&1)
  float sr[4], si[4];
#pragma unroll
  for (int k = 0; k < 4; ++k) { sr[k] = 0.f; si[k] = 0.f; }
  if (l == 0) sr[0] = 1.f;

  float h1[5];
#pragma unroll
  for (int j = 0; j < 5; ++j) h1[j] = 0.f;
  const float* swl = sw + 5 * l * 784;

  // ---- prologue: window (0,0) ----
  float P[4][4];
#pragma unroll
  for (int r = 0; r < 4; ++r) {
    float4 v = *(const float4*)(img + r * 28);
    P[r][0]=v.x; P[r][1]=v.y; P[r][2]=v.z; P[r][3]=v.w;
  }
  float a0, a1, a2, a3, a4;
  pick_angles(P, l, true, true, a0, a1, a2, a3, a4);
  float Wc0, Wc1, Wc2, Wc3;
  build_gate(a0, a1, a2, a3, a4, Wc0, Wc1, Wc2, Wc3);

  int wi = 0, wj = 0;
#pragma unroll 1
  for (int it = 0; it < 196; ++it) {
    // ---- prep next window's pixels + angles (short, branchy, uniform) ----
    if (it != 195) {
      int wjn = wj + 1, win = wi;
      bool fresh = false;
      if (wjn == 14) { wjn = 0; ++win; fresh = true; }
      if (fresh) {
        const int r0 = 2 * win;
        const bool hF = (win != 13);
#pragma unroll
        for (int r = 0; r < 4; ++r) {
          if (r < (hF ? 4 : 2)) {
            float4 v = *(const float4*)(img + (r0 + r) * 28);
            P[r][0]=v.x; P[r][1]=v.y; P[r][2]=v.z; P[r][3]=v.w;
          } else { P[r][0]=0.f; P[r][1]=0.f; P[r][2]=0.f; P[r][3]=0.f; }
        }
      } else {
        const bool hF = (wi != 13);
#pragma unroll
        for (int r = 0; r < 4; ++r) { P[r][0] = P[r][2]; P[r][1] = P[r][3]; }
        const int c0 = 2 * wjn + 2;
        if (c0 < 28) {
#pragma unroll
          for (int r = 0; r < 4; ++r) {
            if (r < (hF ? 4 : 2)) {
              float2 v = *(const float2*)(img + (2*win + r) * 28 + c0);
              P[r][2] = v.x; P[r][3] = v.y;
            } else { P[r][2] = 0.f; P[r][3] = 0.f; }
          }
        } else {
#pragma unroll
          for (int r = 0; r < 4; ++r) { P[r][2] = 0.f; P[r][3] = 0.f; }
        }
      }
      pick_angles(P, l, (win != 13), (wjn != 13), a0, a1, a2, a3, a4);
      wi = win; wj = wjn;
    }

    // ---- straight-line block: build next gate (indep) + apply current gate ----
    float Wn0, Wn1, Wn2, Wn3;
    build_gate(a0, a1, a2, a3, a4, Wn0, Wn1, Wn2, Wn3);   // stale/unused at it=195

    // wire 0 (partner lane^2, row bit = l>>1)
    {
      float w0r = dppf<QP_BC0>(Wc0), w0i = dppf<QP_BC0>(Wc1);
      float w1r = dppf<QP_BC0>(Wc2), w1i = dppf<QP_BC0>(Wc3);
      float uar = sxor(w0r, sm0), uai = w0i;
      float ubr = w1r,            ubi = sxor(w1i, sm0);
#pragma unroll
      for (int k = 0; k < 4; ++k) {
        float pr = dppf<QP_XOR2>(sr[k]), pi = dppf<QP_XOR2>(si[k]);
        float ar = sr[k], ai = si[k];
        sr[k] = uar*ar - uai*ai + ubr*pr - ubi*pi;
        si[k] = uar*ai + uai*ar + ubr*pi + ubi*pr;
      }
    }
    // wire 1 (partner lane^1, row bit = l&1)
    {
      float w0r = dppf<QP_BC1>(Wc0), w0i = dppf<QP_BC1>(Wc1);
      float w1r = dppf<QP_BC1>(Wc2), w1i = dppf<QP_BC1>(Wc3);
      float uar = sxor(w0r, sm1), uai = w0i;
      float ubr = w1r,            ubi = sxor(w1i, sm1);
#pragma unroll
      for (int k = 0; k < 4; ++k) {
        float pr = dppf<QP_XOR1>(sr[k]), pi = dppf<QP_XOR1>(si[k]);
        float ar = sr[k], ai = si[k];
        sr[k] = uar*ar - uai*ai + ubr*pr - ubi*pi;
        si[k] = uar*ai + uai*ar + ubr*pi + ubi*pr;
      }
    }
    // wire 2 (local pairs (k, k+2)): lo'=w0·lo+w1·hi ; hi'=conj(w1)·lo−conj(w0)·hi
    {
      float w0r = dppf<QP_BC2>(Wc0), w0i = dppf<QP_BC2>(Wc1);
      float w1r = dppf<QP_BC2>(Wc2), w1i = dppf<QP_BC2>(Wc3);
#pragma unroll
      for (int k = 0; k < 2; ++k) {
        float lr = sr[k], li = si[k], hr = sr[k+2], hi = si[k+2];
        sr[k]   = w0r*lr - w0i*li + w1r*hr - w1i*hi;
        si[k]   = w0r*li + w0i*lr + w1r*hi + w1i*hr;
        sr[k+2] = w1r*lr + w1i*li - w0r*hr - w0i*hi;
        si[k+2] = w1r*li - w1i*lr - w0r*hi + w0i*hr;
      }
    }
    // wire 3 (local pairs (k, k+1))
    {
      float w0r = dppf<QP_BC3>(Wc0), w0i = dppf<QP_BC3>(Wc1);
      float w1r = dppf<QP_BC3>(Wc2), w1i = dppf<QP_BC3>(Wc3);
#pragma unroll
      for (int k = 0; k < 4; k += 2) {
        float lr = sr[k], li = si[k], hr = sr[k+1], hi = si[k+1];
        sr[k]   = w0r*lr - w0i*li + w1r*hr - w1i*hi;
        si[k]   = w0r*li + w0i*lr + w1r*hi + w1i*hr;
        sr[k+1] = w1r*lr + w1i*li - w0r*hr - w0i*hi;
        si[k+1] = w1r*li - w1i*lr - w0r*hi + w0i*hr;
      }
    }

    // CRZ ring diagonal
#pragma unroll
    for (int k = 0; k < 4; ++k) {
      float r = sr[k], im = si[k];
      sr[k] = czk[k]*r - szk[k]*im;
      si[k] = czk[k]*im + szk[k]*r;
    }

    // Ry(ryt) wires 0,1 (cross-lane)
#pragma unroll
    for (int k = 0; k < 4; ++k) {
      float pr = dppf<QP_XOR2>(sr[k]), pi = dppf<QP_XOR2>(si[k]);
      sr[k] = cry*sr[k] + sgn0*pr;
      si[k] = cry*si[k] + sgn0*pi;
    }
#pragma unroll
    for (int k = 0; k < 4; ++k) {
      float pr = dppf<QP_XOR1>(sr[k]), pi = dppf<QP_XOR1>(si[k]);
      sr[k] = cry*sr[k] + sgn1*pr;
      si[k] = cry*si[k] + sgn1*pi;
    }
    // Ry wires 2,3 (local)
#pragma unroll
    for (int k = 0; k < 2; ++k) {
      float ar=sr[k], br=sr[k+2];  sr[k]=cry*ar - sry*br;  sr[k+2]=sry*ar + cry*br;
      float ai=si[k], bi=si[k+2];  si[k]=cry*ai - sry*bi;  si[k+2]=sry*ai + cry*bi;
    }
#pragma unroll
    for (int k = 0; k < 4; k += 2) {
      float ar=sr[k], br=sr[k+1];  sr[k]=cry*ar - sry*br;  sr[k+1]=sry*ar + cry*br;
      float ai=si[k], bi=si[k+1];  si[k]=cry*ai - sry*bi;  si[k+1]=sry*ai + cry*bi;
    }

    // Z expectations + quad butterfly
    float p0 = sr[0]*sr[0] + si[0]*si[0];
    float p1 = sr[1]*sr[1] + si[1]*si[1];
    float p2 = sr[2]*sr[2] + si[2]*si[2];
    float p3 = sr[3]*sr[3] + si[3]*si[3];
    float s01 = p0 + p1, s23 = p2 + p3;
    float t   = s01 + s23;
    float o0 = (l & 2) ? -t : t;
    float o1 = (l & 1) ? -t : t;
    float o2 = s01 - s23;
    float o3 = (p0 - p1) + (p2 - p3);
    o0 += dppf<QP_XOR1>(o0); o0 += dppf<QP_XOR2>(o0);
    o1 += dppf<QP_XOR1>(o1); o1 += dppf<QP_XOR2>(o1);
    o2 += dppf<QP_XOR1>(o2); o2 += dppf<QP_XOR2>(o2);
    o3 += dppf<QP_XOR1>(o3); o3 += dppf<QP_XOR2>(o3);

    // fc1 partial: this lane's 5 rows
#pragma unroll
    for (int j = 0; j < 5; ++j) {
      float4 wv = *(const float4*)(swl + j * 784 + it * 4);
      h1[j] = fmaf(wv.x, o0, fmaf(wv.y, o1, fmaf(wv.z, o2, fmaf(wv.w, o3, h1[j]))));
    }

    // rotate pipeline
    Wc0 = Wn0; Wc1 = Wn1; Wc2 = Wn2; Wc3 = Wn3;
  }

  // ---- epilogue: bias + leaky relu + fc2, reduce over group ----
  float pa = 0.f, pb = 0.f;
#pragma unroll
  for (int j = 0; j < 5; ++j) {
    const int r = 5 * l + j;
    float v = h1[j] + fc1_b[r];
    v = (v > 0.f) ? v : 0.1f * v;
    pa = fmaf(fc2_w[r],      v, pa);
    pb = fmaf(fc2_w[20 + r], v, pb);
  }
  pa += dppf<QP_XOR1>(pa); pa += dppf<QP_XOR2>(pa);
  pb += dppf<QP_XOR1>(pb); pb += dppf<QP_XOR2>(pb);
  if (l == 0) {
    float2 res; res.x = pa + fc2_b[0]; res.y = pb + fc2_b[1];
    *(float2*)(out + (size_t)b * 2) = res;
  }
}

extern "C" void kernel_launch(void* const* d_in, const int* in_sizes, int n_in,
                              void* d_out, int out_size, void* d_ws, size_t ws_size,
                              hipStream_t stream) {
  const float* x      = (const float*)d_in[0];
  const float* crz_t  = (const float*)d_in[1];
  const float* ry_t   = (const float*)d_in[2];
  const float* fc1_w  = (const float*)d_in[3];
  const float* fc1_b  = (const float*)d_in[4];
  const float* fc2_w  = (const float*)d_in[5];
  const float* fc2_b  = (const float*)d_in[6];
  float* out = (float*)d_out;
  const int B = in_sizes[0] / 784;
  const int grid = (B * 4 + 255) / 256;
  quanv_kernel<<<grid, 256, 0, stream>>>(x, crz_t, ry_t, fc1_w, fc1_b,
                                         fc2_w, fc2_b, out, B);
}

// Round 5
// 276.847 us; speedup vs baseline: 1.8387x; 1.8387x over previous
//
#include <hip/hip_runtime.h>

#define RS2f 0.70710678118654752f

// DPP quad_perm encodings: sel0 | sel1<<2 | sel2<<4 | sel3<<6
#define QP_XOR1 0xB1   // [1,0,3,2]
#define QP_XOR2 0x4E   // [2,3,0,1]
#define QP_BC0  0x00
#define QP_BC1  0x55
#define QP_BC2  0xAA
#define QP_BC3  0xFF

template<int CTRL> __device__ __forceinline__ float dppf(float x) {
  return __int_as_float(__builtin_amdgcn_update_dpp(
      0, __float_as_int(x), CTRL, 0xF, 0xF, true));
}

__device__ __forceinline__ float sxor(float x, int sm) {
  return __int_as_float(__float_as_int(x) ^ sm);
}

// Build row0 of U = RZ(a4)RY(a3)RZ(a2)RY(a1)RZ(a0)·H.
// The RZ/RY chain is SU(2) [[α,β],[−β*,α*]]; track (α,β) only.
// U row0 = rs2·(α+β, α−β); row1 of U = (conj(w1), −conj(w0)) derived at apply.
__device__ __forceinline__ void build_gate(float a0, float a1, float a2, float a3, float a4,
                                           float &w0r, float &w0i, float &w1r, float &w1i) {
  float s, c;
  __sincosf(0.5f*a0, &s, &c);
  float ar = c, ai = -s, br = 0.f, bi = 0.f;     // S = RZ(a0)
  // RY(a): α' = cα + sβ*, β' = cβ − sα*   (verified round 4)
  __sincosf(0.5f*a1, &s, &c);
  { float tar = c*ar + s*br, tai = c*ai - s*bi;
    float tbr = c*br - s*ar, tbi = c*bi + s*ai;
    ar=tar; ai=tai; br=tbr; bi=tbi; }
  // RZ(a): row0 entries of S: α *= e^{-ia/2}, β *= e^{-ia/2}
  __sincosf(0.5f*a2, &s, &c);
  { float t;
    t=ar; ar = c*t + s*ai; ai = c*ai - s*t;
    t=br; br = c*t + s*bi; bi = c*bi - s*t; }
  __sincosf(0.5f*a3, &s, &c);
  { float tar = c*ar + s*br, tai = c*ai - s*bi;
    float tbr = c*br - s*ar, tbi = c*bi + s*ai;
    ar=tar; ai=tai; br=tbr; bi=tbi; }
  __sincosf(0.5f*a4, &s, &c);
  { float t;
    t=ar; ar = c*t + s*ai; ai = c*ai - s*t;
    t=br; br = c*t + s*bi; bi = c*bi - s*t; }
  // ·H fold
  w0r = RS2f*(ar+br); w0i = RS2f*(ai+bi);
  w1r = RS2f*(ar-br); w1i = RS2f*(ai-bi);
}

__global__ void __launch_bounds__(256)
quanv_kernel(const float* __restrict__ x,
             const float* __restrict__ crz_t,
             const float* __restrict__ ry_t,
             const float* __restrict__ fc1_w,
             const float* __restrict__ fc1_b,
             const float* __restrict__ fc2_w,
             const float* __restrict__ fc2_b,
             float* __restrict__ out, int B)
{
  __shared__ float sw[20 * 784];
  const int tid = threadIdx.x;
  for (int i = tid; i < (20 * 784) / 4; i += 256)
    ((float4*)sw)[i] = ((const float4*)fc1_w)[i];
  __syncthreads();

  const int l = tid & 3;                       // lane within 4-lane group
  const int b = (blockIdx.x * 256 + tid) >> 2; // element id
  if (b >= B) return;
  const float* img = x + (size_t)b * 784;

  // ---- uniform scalar-derived constants ----
  const float theta = crz_t[0];
  const float ryt   = ry_t[0];
  float cry, sry;
  __sincosf(0.5f * ryt, &sry, &cry);
  const float sgn0 = (l & 2) ? sry : -sry;   // Ry wire0 partner sign (bit = l>>1)
  const float sgn1 = (l & 1) ? sry : -sry;   // Ry wire1 partner sign (bit = l&1)
  const int sm0 = (l & 2) ? (int)0x80000000 : 0;  // wire0 row-bit sign mask
  const int sm1 = (l & 1) ? (int)0x80000000 : 0;  // wire1 row-bit sign mask

  // CRZ ring diag exp(0.5i*theta*sg[n]) for this lane's 4 amps (n = 4l+k)
  float g0,g1,g2,g3;
  if      (l == 0) { g0= 0.f; g1=-1.f; g2=-1.f; g3=0.f; }
  else if (l == 1) { g0=-1.f; g1=-2.f; g2= 0.f; g3=1.f; }
  else if (l == 2) { g0=-1.f; g1= 0.f; g2=-2.f; g3=1.f; }
  else             { g0= 0.f; g1= 1.f; g2= 1.f; g3=4.f; }
  float czk[4], szk[4];
  __sincosf(0.5f*theta*g0, &szk[0], &czk[0]);
  __sincosf(0.5f*theta*g1, &szk[1], &czk[1]);
  __sincosf(0.5f*theta*g2, &szk[2], &czk[2]);
  __sincosf(0.5f*theta*g3, &szk[3], &czk[3]);

  // state: amp n = 4*l + k  (bits: b0=l>>1, b1=l&1, b2=k>>1, b3=k&1)
  float sr[4], si[4];
#pragma unroll
  for (int k = 0; k < 4; ++k) { sr[k] = 0.f; si[k] = 0.f; }
  if (l == 0) sr[0] = 1.f;

  float h1[5];
#pragma unroll
  for (int j = 0; j < 5; ++j) h1[j] = 0.f;
  const float* swl = sw + 5 * l * 784;

  for (int wi = 0; wi < 14; ++wi) {
    const int r0 = 2 * wi;
    const bool hFull = (wi != 13);             // valid rows: 4 or 2
    float P[4][4];
#pragma unroll
    for (int r = 0; r < 4; ++r) {
      if (r < (hFull ? 4 : 2)) {
        float4 v = *(const float4*)(img + (r0 + r) * 28);
        P[r][0]=v.x; P[r][1]=v.y; P[r][2]=v.z; P[r][3]=v.w;
      } else {
        P[r][0]=0.f; P[r][1]=0.f; P[r][2]=0.f; P[r][3]=0.f;
      }
    }

    for (int wj = 0; wj < 14; ++wj) {
      if (wj > 0) {
#pragma unroll
        for (int r = 0; r < 4; ++r) { P[r][0] = P[r][2]; P[r][1] = P[r][3]; }
        const int c0 = 2 * wj + 2;
        if (c0 < 28) {
#pragma unroll
          for (int r = 0; r < 4; ++r) {
            if (r < (hFull ? 4 : 2)) {
              float2 v = *(const float2*)(img + (r0 + r) * 28 + c0);
              P[r][2] = v.x; P[r][3] = v.y;
            } else { P[r][2] = 0.f; P[r][3] = 0.f; }
          }
        } else {
#pragma unroll
          for (int r = 0; r < 4; ++r) { P[r][2] = 0.f; P[r][3] = 0.f; }
        }
      }
      const bool wFull = (wj != 13);

      // ---- per-lane angle pick (inline, round-3 style): lane l gets f[5l..5l+4] ----
      float a0=0.f, a1=0.f, a2=0.f, a3=0.f, a4=0.f;
      if (hFull && wFull) {                    // f[k] = P[k>>2][k&3]
        if      (l == 0) { a0=P[0][0]; a1=P[0][1]; a2=P[0][2]; a3=P[0][3]; a4=P[1][0]; }
        else if (l == 1) { a0=P[1][1]; a1=P[1][2]; a2=P[1][3]; a3=P[2][0]; a4=P[2][1]; }
        else if (l == 2) { a0=P[2][2]; a1=P[2][3]; a2=P[3][0]; a3=P[3][1]; a4=P[3][2]; }
        else             { a0=P[3][3]; }
      } else if (hFull) {                      // w==2
        if      (l == 0) { a0=P[0][0]; a1=P[0][1]; a2=P[1][0]; a3=P[1][1]; a4=P[2][0]; }
        else if (l == 1) { a0=P[2][1]; a1=P[3][0]; a2=P[3][1]; }
      } else if (wFull) {                      // h==2
        if      (l == 0) { a0=P[0][0]; a1=P[0][1]; a2=P[0][2]; a3=P[0][3]; a4=P[1][0]; }
        else if (l == 1) { a0=P[1][1]; a1=P[1][2]; a2=P[1][3]; }
      } else {                                 // h==2, w==2
        if      (l == 0) { a0=P[0][0]; a1=P[0][1]; a2=P[1][0]; a3=P[1][1]; }
      }

      // ---- lane l builds row0 of U for wire l ----
      float W0, W1, W2, W3;
      build_gate(a0, a1, a2, a3, a4, W0, W1, W2, W3);

      // ---- wire 0 (partner lane^2, row bit = l>>1) ----
      {
        float w0r = dppf<QP_BC0>(W0), w0i = dppf<QP_BC0>(W1);
        float w1r = dppf<QP_BC0>(W2), w1i = dppf<QP_BC0>(W3);
        float uar = sxor(w0r, sm0), uai = w0i;
        float ubr = w1r,            ubi = sxor(w1i, sm0);
#pragma unroll
        for (int k = 0; k < 4; ++k) {
          float pr = dppf<QP_XOR2>(sr[k]), pi = dppf<QP_XOR2>(si[k]);
          float ar = sr[k], ai = si[k];
          sr[k] = uar*ar - uai*ai + ubr*pr - ubi*pi;
          si[k] = uar*ai + uai*ar + ubr*pi + ubi*pr;
        }
      }
      // ---- wire 1 (partner lane^1, row bit = l&1) ----
      {
        float w0r = dppf<QP_BC1>(W0), w0i = dppf<QP_BC1>(W1);
        float w1r = dppf<QP_BC1>(W2), w1i = dppf<QP_BC1>(W3);
        float uar = sxor(w0r, sm1), uai = w0i;
        float ubr = w1r,            ubi = sxor(w1i, sm1);
#pragma unroll
        for (int k = 0; k < 4; ++k) {
          float pr = dppf<QP_XOR1>(sr[k]), pi = dppf<QP_XOR1>(si[k]);
          float ar = sr[k], ai = si[k];
          sr[k] = uar*ar - uai*ai + ubr*pr - ubi*pi;
          si[k] = uar*ai + uai*ar + ubr*pi + ubi*pr;
        }
      }
      // ---- wire 2 (local pairs (k,k+2)): lo'=w0·lo+w1·hi ; hi'=conj(w1)·lo−conj(w0)·hi ----
      {
        float w0r = dppf<QP_BC2>(W0), w0i = dppf<QP_BC2>(W1);
        float w1r = dppf<QP_BC2>(W2), w1i = dppf<QP_BC2>(W3);
#pragma unroll
        for (int k = 0; k < 2; ++k) {
          float lr = sr[k], li = si[k], hr = sr[k+2], hi = si[k+2];
          sr[k]   = w0r*lr - w0i*li + w1r*hr - w1i*hi;
          si[k]   = w0r*li + w0i*lr + w1r*hi + w1i*hr;
          sr[k+2] = w1r*lr + w1i*li - w0r*hr - w0i*hi;
          si[k+2] = w1r*li - w1i*lr - w0r*hi + w0i*hr;
        }
      }
      // ---- wire 3 (local pairs (k,k+1)) ----
      {
        float w0r = dppf<QP_BC3>(W0), w0i = dppf<QP_BC3>(W1);
        float w1r = dppf<QP_BC3>(W2), w1i = dppf<QP_BC3>(W3);
#pragma unroll
        for (int k = 0; k < 4; k += 2) {
          float lr = sr[k], li = si[k], hr = sr[k+1], hi = si[k+1];
          sr[k]   = w0r*lr - w0i*li + w1r*hr - w1i*hi;
          si[k]   = w0r*li + w0i*lr + w1r*hi + w1i*hr;
          sr[k+1] = w1r*lr + w1i*li - w0r*hr - w0i*hi;
          si[k+1] = w1r*li - w1i*lr - w0r*hi + w0i*hr;
        }
      }

      // ---- CRZ ring diagonal ----
#pragma unroll
      for (int k = 0; k < 4; ++k) {
        float r = sr[k], im = si[k];
        sr[k] = czk[k]*r - szk[k]*im;
        si[k] = czk[k]*im + szk[k]*r;
      }

      // ---- Ry(ryt) wires 0,1 (cross-lane) ----
#pragma unroll
      for (int k = 0; k < 4; ++k) {
        float pr = dppf<QP_XOR2>(sr[k]), pi = dppf<QP_XOR2>(si[k]);
        sr[k] = cry*sr[k] + sgn0*pr;
        si[k] = cry*si[k] + sgn0*pi;
      }
#pragma unroll
      for (int k = 0; k < 4; ++k) {
        float pr = dppf<QP_XOR1>(sr[k]), pi = dppf<QP_XOR1>(si[k]);
        sr[k] = cry*sr[k] + sgn1*pr;
        si[k] = cry*si[k] + sgn1*pi;
      }
      // ---- Ry wires 2,3 (local) ----
#pragma unroll
      for (int k = 0; k < 2; ++k) {
        float ar=sr[k], br=sr[k+2];  sr[k]=cry*ar - sry*br;  sr[k+2]=sry*ar + cry*br;
        float ai=si[k], bi=si[k+2];  si[k]=cry*ai - sry*bi;  si[k+2]=sry*ai + cry*bi;
      }
#pragma unroll
      for (int k = 0; k < 4; k += 2) {
        float ar=sr[k], br=sr[k+1];  sr[k]=cry*ar - sry*br;  sr[k+1]=sry*ar + cry*br;
        float ai=si[k], bi=si[k+1];  si[k]=cry*ai - sry*bi;  si[k+1]=sry*ai + cry*bi;
      }

      // ---- Z expectations + quad butterfly ----
      float p0 = sr[0]*sr[0] + si[0]*si[0];
      float p1 = sr[1]*sr[1] + si[1]*si[1];
      float p2 = sr[2]*sr[2] + si[2]*si[2];
      float p3 = sr[3]*sr[3] + si[3]*si[3];
      float s01 = p0 + p1, s23 = p2 + p3;
      float t   = s01 + s23;
      float o0 = (l & 2) ? -t : t;
      float o1 = (l & 1) ? -t : t;
      float o2 = s01 - s23;
      float o3 = (p0 - p1) + (p2 - p3);
      o0 += dppf<QP_XOR1>(o0); o0 += dppf<QP_XOR2>(o0);
      o1 += dppf<QP_XOR1>(o1); o1 += dppf<QP_XOR2>(o1);
      o2 += dppf<QP_XOR1>(o2); o2 += dppf<QP_XOR2>(o2);
      o3 += dppf<QP_XOR1>(o3); o3 += dppf<QP_XOR2>(o3);

      // ---- fc1 partial: this lane's 5 rows ----
      const int win4 = (wi * 14 + wj) * 4;
#pragma unroll
      for (int j = 0; j < 5; ++j) {
        float4 wv = *(const float4*)(swl + j * 784 + win4);
        h1[j] = fmaf(wv.x, o0, fmaf(wv.y, o1, fmaf(wv.z, o2, fmaf(wv.w, o3, h1[j]))));
      }
    }
  }

  // ---- epilogue: bias + leaky relu + fc2, reduce over group ----
  float pa = 0.f, pb = 0.f;
#pragma unroll
  for (int j = 0; j < 5; ++j) {
    const int r = 5 * l + j;
    float v = h1[j] + fc1_b[r];
    v = (v > 0.f) ? v : 0.1f * v;
    pa = fmaf(fc2_w[r],      v, pa);
    pb = fmaf(fc2_w[20 + r], v, pb);
  }
  pa += dppf<QP_XOR1>(pa); pa += dppf<QP_XOR2>(pa);
  pb += dppf<QP_XOR1>(pb); pb += dppf<QP_XOR2>(pb);
  if (l == 0) {
    float2 res; res.x = pa + fc2_b[0]; res.y = pb + fc2_b[1];
    *(float2*)(out + (size_t)b * 2) = res;
  }
}

extern "C" void kernel_launch(void* const* d_in, const int* in_sizes, int n_in,
                              void* d_out, int out_size, void* d_ws, size_t ws_size,
                              hipStream_t stream) {
  const float* x      = (const float*)d_in[0];
  const float* crz_t  = (const float*)d_in[1];
  const float* ry_t   = (const float*)d_in[2];
  const float* fc1_w  = (const float*)d_in[3];
  const float* fc1_b  = (const float*)d_in[4];
  const float* fc2_w  = (const float*)d_in[5];
  const float* fc2_b  = (const float*)d_in[6];
  float* out = (float*)d_out;
  const int B = in_sizes[0] / 784;
  const int grid = (B * 4 + 255) / 256;
  quanv_kernel<<<grid, 256, 0, stream>>>(x, crz_t, ry_t, fc1_w, fc1_b,
                                         fc2_w, fc2_b, out, B);
}